// Round 1
// baseline (397.556 us; speedup 1.0000x reference)
//
#include <hip/hip_runtime.h>

// ---------- types ----------
typedef __bf16 bf16x8 __attribute__((ext_vector_type(8)));
typedef float  f32x4  __attribute__((ext_vector_type(4)));

__device__ __forceinline__ unsigned short f2bf(float f) {
  unsigned int u = __builtin_bit_cast(unsigned int, f);
  u = (u + 0x7FFFu + ((u >> 16) & 1u)) >> 16;   // RNE
  return (unsigned short)u;
}
__device__ __forceinline__ float bf2f(unsigned short h) {
  return __builtin_bit_cast(float, (unsigned int)h << 16);
}

// async global->LDS, 16B per lane; LDS base must be wave-uniform
__device__ __forceinline__ void gload_lds16(const void* g, void* l) {
  __builtin_amdgcn_global_load_lds(
      (__attribute__((address_space(1))) void*)(unsigned long long)g,
      (__attribute__((address_space(3))) void*)(unsigned int)(unsigned long long)l,
      16, 0, 0);
}

// ---------- GEMM: C = A[M,K] * Bt[N,K]^T ----------
// 128x128 tile, BK=32, 256 threads (4 waves, 2x2 wave grid, 64x64 per wave)
#define BM 128
#define BN 128
#define BK 32

// OUT_MODE: 0 = fp32, 1 = bf16, 2 = fp32 + bias
template<int OUT_MODE, bool CAUSAL_TRI, bool CAUSAL_K>
__global__ __launch_bounds__(256) void gemm_bt(
    const unsigned short* __restrict__ A, const unsigned short* __restrict__ Bt,
    void* __restrict__ Cv, const float* __restrict__ bias,
    int M, int N, int K, int lda, int ldb, int ldc,
    long long sA, long long sBt, long long sC)
{
  const int m0 = blockIdx.y * BM;
  const int n0 = blockIdx.x * BN;
  if (CAUSAL_TRI && n0 > m0) return;   // above-diagonal tile: never read
  const int zb = blockIdx.z;
  A  += (long long)zb * sA;
  Bt += (long long)zb * sBt;

  __shared__ unsigned short As[BM * BK];   // [row][k] linear
  __shared__ unsigned short Bs[BN * BK];   // [col][k] linear

  const int tid  = threadIdx.x;
  const int wave = tid >> 6;
  const int lane = tid & 63;
  const int wr   = wave >> 1;        // wave row 0..1
  const int wc   = wave & 1;         // wave col 0..1
  const int ln15 = lane & 15;
  const int kq   = lane >> 4;        // 0..3

  f32x4 acc[4][4];
  #pragma unroll
  for (int i = 0; i < 4; ++i)
    #pragma unroll
    for (int j = 0; j < 4; ++j) {
      f32x4 z = {0.f, 0.f, 0.f, 0.f};
      acc[i][j] = z;
    }

  int Keff = K;
  if (CAUSAL_K) { int lim = m0 + BM; Keff = (K < lim) ? K : lim; }
  const int kTiles = Keff / BK;

  const int ar0 = tid >> 2;            // staging row (call 0)
  const int ac0 = (tid & 3) << 3;      // staging col (8 elems)

  for (int kt = 0; kt < kTiles; ++kt) {
    const int k0 = kt * BK;
    // stage A tile (128x32) and B tile (128x32), 16B/lane, 2 calls each
    gload_lds16(A  + (size_t)(m0 + ar0)      * lda + (k0 + ac0), As + wave * 512);
    gload_lds16(A  + (size_t)(m0 + 64 + ar0) * lda + (k0 + ac0), As + 2048 + wave * 512);
    gload_lds16(Bt + (size_t)(n0 + ar0)      * ldb + (k0 + ac0), Bs + wave * 512);
    gload_lds16(Bt + (size_t)(n0 + 64 + ar0) * ldb + (k0 + ac0), Bs + 2048 + wave * 512);
    __syncthreads();   // compiler drains vmcnt before s_barrier

    bf16x8 af[4], bfr[4];
    #pragma unroll
    for (int i = 0; i < 4; ++i) {
      af[i]  = *reinterpret_cast<const bf16x8*>(&As[(wr * 64 + i * 16 + ln15) * BK + kq * 8]);
      bfr[i] = *reinterpret_cast<const bf16x8*>(&Bs[(wc * 64 + i * 16 + ln15) * BK + kq * 8]);
    }
    #pragma unroll
    for (int i = 0; i < 4; ++i)
      #pragma unroll
      for (int j = 0; j < 4; ++j)
        acc[i][j] = __builtin_amdgcn_mfma_f32_16x16x32_bf16(af[i], bfr[j], acc[i][j], 0, 0, 0);
    __syncthreads();   // protect LDS before next stage
  }

  // epilogue: C/D layout col = lane&15, row = (lane>>4)*4 + reg
  const int crow0 = m0 + wr * 64;
  const int ccol0 = n0 + wc * 64;
  float bvals[4] = {0.f, 0.f, 0.f, 0.f};
  if (OUT_MODE == 2) {
    #pragma unroll
    for (int j = 0; j < 4; ++j) bvals[j] = bias[ccol0 + j * 16 + ln15];
  }
  #pragma unroll
  for (int i = 0; i < 4; ++i) {
    const int r0 = crow0 + i * 16 + kq * 4;
    #pragma unroll
    for (int j = 0; j < 4; ++j) {
      const int c = ccol0 + j * 16 + ln15;
      #pragma unroll
      for (int rr = 0; rr < 4; ++rr) {
        const float vvv = acc[i][j][rr] + bvals[j];
        if (OUT_MODE == 1) {
          unsigned short* C = (unsigned short*)Cv + (long long)zb * sC;
          C[(size_t)(r0 + rr) * ldc + c] = f2bf(vvv);
        } else {
          float* C = (float*)Cv + (long long)zb * sC;
          C[(size_t)(r0 + rr) * ldc + c] = vvv;
        }
      }
    }
  }
}

// ---------- helpers ----------
__global__ __launch_bounds__(256) void cast_f32_bf16(
    const float* __restrict__ in, unsigned short* __restrict__ out, long long n) {
  long long i = ((long long)blockIdx.x * 256 + threadIdx.x) * 4;
  if (i + 4 <= n) {
    const float4 v = *reinterpret_cast<const float4*>(in + i);
    ushort4 o;
    o.x = f2bf(v.x); o.y = f2bf(v.y); o.z = f2bf(v.z); o.w = f2bf(v.w);
    *reinterpret_cast<ushort4*>(out + i) = o;
  } else {
    for (; i < n; ++i) out[i] = f2bf(in[i]);
  }
}

// WT[o][i] = bf16(W[i][o]); 32x32 tiles via LDS
__global__ void transcast_w(const float* __restrict__ W, unsigned short* __restrict__ WT,
                            int rows, int cols) {
  __shared__ float tile[32][33];
  const int c0 = blockIdx.x * 32, r0 = blockIdx.y * 32;
  const int tx = threadIdx.x, ty = threadIdx.y;
  #pragma unroll
  for (int r = ty; r < 32; r += 8)
    tile[r][tx] = W[(size_t)(r0 + r) * cols + (c0 + tx)];
  __syncthreads();
  #pragma unroll
  for (int r = ty; r < 32; r += 8)
    WT[(size_t)(c0 + r) * rows + (r0 + tx)] = f2bf(tile[tx][r]);
}

// per-batch bf16 transpose: VT[b][d][n] = V[b][n][d]
__global__ void trans_bf16(const unsigned short* __restrict__ V, unsigned short* __restrict__ VT,
                           int rows, int cols) {
  const size_t bo = (size_t)blockIdx.z * rows * cols;
  __shared__ unsigned short tile[32][33];
  const int c0 = blockIdx.x * 32, r0 = blockIdx.y * 32;
  const int tx = threadIdx.x, ty = threadIdx.y;
  #pragma unroll
  for (int r = ty; r < 32; r += 8)
    tile[r][tx] = V[bo + (size_t)(r0 + r) * cols + (c0 + tx)];
  __syncthreads();
  #pragma unroll
  for (int r = ty; r < 32; r += 8)
    VT[bo + (size_t)(c0 + r) * rows + (r0 + tx)] = tile[tx][r];
}

// causal row softmax: att[j] = softmax(S[0..r]*scale), zero-fill to 128 boundary
__global__ __launch_bounds__(256) void softmax_causal(
    const float* __restrict__ S, unsigned short* __restrict__ att, int N, float scale) {
  const int row = blockIdx.x;
  const int b = row / N;
  const int r = row - b * N;
  const float* s = S + (size_t)b * N * N + (size_t)r * N;
  unsigned short* a = att + (size_t)b * N * N + (size_t)r * N;
  const int L = r + 1;
  const int tid = threadIdx.x;
  __shared__ float red[4];

  float mx = -3.0e38f;
  for (int j = tid; j < L; j += 256) mx = fmaxf(mx, s[j]);
  #pragma unroll
  for (int o = 32; o > 0; o >>= 1) mx = fmaxf(mx, __shfl_xor(mx, o, 64));
  if ((tid & 63) == 0) red[tid >> 6] = mx;
  __syncthreads();
  mx = fmaxf(fmaxf(red[0], red[1]), fmaxf(red[2], red[3]));
  __syncthreads();

  float sum = 0.f;
  for (int j = tid; j < L; j += 256) sum += __expf((s[j] - mx) * scale);
  #pragma unroll
  for (int o = 32; o > 0; o >>= 1) sum += __shfl_xor(sum, o, 64);
  if ((tid & 63) == 0) red[tid >> 6] = sum;
  __syncthreads();
  sum = red[0] + red[1] + red[2] + red[3];
  const float inv = 1.f / sum;

  const int Lpad = (L + 127) & ~127;   // PV reads k < roundup(row+1,128)
  for (int j = tid; j < Lpad; j += 256) {
    const float p = (j < L) ? __expf((s[j] - mx) * scale) * inv : 0.f;
    a[j] = f2bf(p);
  }
}

// h = LN(attout + v) * gamma + beta  (D=1024, 256 thr x 4)
__global__ __launch_bounds__(256) void add_layernorm(
    const unsigned short* __restrict__ ao, const unsigned short* __restrict__ v,
    const float* __restrict__ gamma, const float* __restrict__ beta,
    unsigned short* __restrict__ h) {
  const size_t base = (size_t)blockIdx.x * 1024;
  const int tid = threadIdx.x;
  float xv[4];
  float sum = 0.f, sq = 0.f;
  #pragma unroll
  for (int k = 0; k < 4; ++k) {
    const int j = tid + k * 256;
    const float t = bf2f(ao[base + j]) + bf2f(v[base + j]);
    xv[k] = t; sum += t; sq += t * t;
  }
  #pragma unroll
  for (int o = 32; o > 0; o >>= 1) { sum += __shfl_xor(sum, o, 64); sq += __shfl_xor(sq, o, 64); }
  __shared__ float rs_[4], rq_[4];
  if ((tid & 63) == 0) { rs_[tid >> 6] = sum; rq_[tid >> 6] = sq; }
  __syncthreads();
  sum = rs_[0] + rs_[1] + rs_[2] + rs_[3];
  sq  = rq_[0] + rq_[1] + rq_[2] + rq_[3];
  const float mu   = sum * (1.f / 1024.f);
  const float var  = sq * (1.f / 1024.f) - mu * mu;
  const float rstd = rsqrtf(var + 1e-5f);
  #pragma unroll
  for (int k = 0; k < 4; ++k) {
    const int j = tid + k * 256;
    h[base + j] = f2bf((xv[k] - mu) * rstd * gamma[j] + beta[j]);
  }
}

// ---------- launch ----------
extern "C" void kernel_launch(void* const* d_in, const int* in_sizes, int n_in,
                              void* d_out, int out_size, void* d_ws, size_t ws_size,
                              hipStream_t stream) {
  const float* x     = (const float*)d_in[0];
  const float* Wq    = (const float*)d_in[1];
  const float* Wk    = (const float*)d_in[2];
  const float* Wv    = (const float*)d_in[3];
  const float* Wfc   = (const float*)d_in[4];
  const float* bfc   = (const float*)d_in[5];
  const float* gamma = (const float*)d_in[6];
  const float* beta  = (const float*)d_in[7];
  float* out = (float*)d_out;

  const int Bn = 4, Nn = 2048, Dn = 1024;
  const int M = Bn * Nn;                       // 8192

  char* ws = (char*)d_ws;
  size_t off = 0;
  auto alloc = [&](size_t bytes) { void* p = ws + off; off += (bytes + 255) & ~255ULL; return p; };
  unsigned short* xb   = (unsigned short*)alloc((size_t)M * Dn * 2);      // 16 MB
  unsigned short* WqT  = (unsigned short*)alloc((size_t)Dn * Dn * 2);
  unsigned short* WkT  = (unsigned short*)alloc((size_t)Dn * Dn * 2);
  unsigned short* WvT  = (unsigned short*)alloc((size_t)Dn * Dn * 2);
  unsigned short* WfcT = (unsigned short*)alloc((size_t)Dn * Dn * 2);
  unsigned short* Qb   = (unsigned short*)alloc((size_t)M * Dn * 2);      // 16 MB
  unsigned short* Kb   = (unsigned short*)alloc((size_t)M * Dn * 2);
  unsigned short* Vb   = (unsigned short*)alloc((size_t)M * Dn * 2);
  unsigned short* VTb  = (unsigned short*)alloc((size_t)M * Dn * 2);
  float*          S    = (float*)alloc((size_t)Bn * Nn * Nn * 4);         // 64 MB
  unsigned short* att  = (unsigned short*)alloc((size_t)Bn * Nn * Nn * 2);// 32 MB
  unsigned short* ao   = Qb;   // reuse: Q dead after scores
  unsigned short* h    = Kb;   // reuse: K dead after scores

  const dim3 blk(256);

  // 1. casts
  cast_f32_bf16<<<dim3(((long long)M * Dn) / 1024), blk, 0, stream>>>(x, xb, (long long)M * Dn);
  const dim3 tb(32, 8, 1), tg(Dn / 32, Dn / 32, 1);
  transcast_w<<<tg, tb, 0, stream>>>(Wq,  WqT,  Dn, Dn);
  transcast_w<<<tg, tb, 0, stream>>>(Wk,  WkT,  Dn, Dn);
  transcast_w<<<tg, tb, 0, stream>>>(Wv,  WvT,  Dn, Dn);
  transcast_w<<<tg, tb, 0, stream>>>(Wfc, WfcT, Dn, Dn);

  // 2. projections: [8192,1024] x [1024,1024]^T -> bf16
  const dim3 gq(Dn / BN, M / BM, 1);
  gemm_bt<1, false, false><<<gq, blk, 0, stream>>>(xb, WqT, Qb, nullptr,
      M, Dn, Dn, Dn, Dn, Dn, 0, 0, 0);
  gemm_bt<1, false, false><<<gq, blk, 0, stream>>>(xb, WkT, Kb, nullptr,
      M, Dn, Dn, Dn, Dn, Dn, 0, 0, 0);
  gemm_bt<1, false, false><<<gq, blk, 0, stream>>>(xb, WvT, Vb, nullptr,
      M, Dn, Dn, Dn, Dn, Dn, 0, 0, 0);

  // 3. V^T for PV
  trans_bf16<<<dim3(Dn / 32, Nn / 32, Bn), tb, 0, stream>>>(Vb, VTb, Nn, Dn);

  // 4. scores = Q K^T (lower-triangle tiles only), fp32
  gemm_bt<0, true, false><<<dim3(Nn / BN, Nn / BM, Bn), blk, 0, stream>>>(Qb, Kb, S, nullptr,
      Nn, Nn, Dn, Dn, Dn, Nn, (long long)Nn * Dn, (long long)Nn * Dn, (long long)Nn * Nn);

  // 5. causal softmax -> bf16 att (zero-padded to tile boundary)
  softmax_causal<<<dim3(Bn * Nn), blk, 0, stream>>>(S, att, Nn, 0.03125f);

  // 6. attout = att @ V  (K limited to diagonal block)
  gemm_bt<1, false, true><<<dim3(Dn / BN, Nn / BM, Bn), blk, 0, stream>>>(att, VTb, ao, nullptr,
      Nn, Dn, Nn, Nn, Nn, Dn, (long long)Nn * Nn, (long long)Nn * Dn, (long long)Nn * Dn);

  // 7. h = LN(attout + v)
  add_layernorm<<<dim3(Bn * Nn), blk, 0, stream>>>(ao, Vb, gamma, beta, h);

  // 8. out = h @ Wfc + bfc, fp32
  gemm_bt<2, false, false><<<gq, blk, 0, stream>>>(h, WfcT, out, bfc,
      M, Dn, Dn, Dn, Dn, Dn, 0, 0, 0);
}

// Round 4
// 339.929 us; speedup vs baseline: 1.1695x; 1.1695x over previous
//
#include <hip/hip_runtime.h>

// ---------- types ----------
typedef __bf16 bf16x8 __attribute__((ext_vector_type(8)));
typedef float  f32x4  __attribute__((ext_vector_type(4)));

__device__ __forceinline__ unsigned short f2bf(float f) {
  unsigned int u = __builtin_bit_cast(unsigned int, f);
  u = (u + 0x7FFFu + ((u >> 16) & 1u)) >> 16;   // RNE
  return (unsigned short)u;
}
__device__ __forceinline__ float bf2f(unsigned short h) {
  return __builtin_bit_cast(float, (unsigned int)h << 16);
}

// async global->LDS, 16B per lane; LDS base must be wave-uniform
__device__ __forceinline__ void gload_lds16(const void* g, void* l) {
  __builtin_amdgcn_global_load_lds(
      (__attribute__((address_space(1))) void*)(unsigned long long)g,
      (__attribute__((address_space(3))) void*)(unsigned int)(unsigned long long)l,
      16, 0, 0);
}

// ---------- GEMM: C = A[M,K] * Bt[N,K]^T ----------
// 128x128 tile, BK=32, 256 threads (4 waves, 2x2 wave grid, 64x64 per wave)
// 2-phase double-buffered: prefetch tile t+1 before computing tile t.
#define BM 128
#define BN 128
#define BK 32

// OUT_MODE: 0 = fp32, 1 = bf16, 2 = fp32 + bias
template<int OUT_MODE, bool CAUSAL_TRI, bool CAUSAL_K>
__global__ __launch_bounds__(256) void gemm_bt(
    const unsigned short* __restrict__ A, const unsigned short* __restrict__ Bt,
    void* __restrict__ Cv, const float* __restrict__ bias,
    int K, int lda, int ldb, int ldc,
    long long sA, long long sBt, long long sC)
{
  const int m0 = blockIdx.y * BM;
  const int n0 = blockIdx.x * BN;
  if (CAUSAL_TRI && n0 > m0) return;   // above-diagonal tile: never computed
  const int zb = blockIdx.z;
  A  += (long long)zb * sA;
  Bt += (long long)zb * sBt;

  __shared__ unsigned short As[2][BM * BK];   // 2 x 8 KB
  __shared__ unsigned short Bs[2][BN * BK];   // 2 x 8 KB

  const int tid  = threadIdx.x;
  const int wave = tid >> 6;
  const int lane = tid & 63;
  const int wr   = wave >> 1;        // wave row 0..1
  const int wc   = wave & 1;         // wave col 0..1
  const int ln15 = lane & 15;
  const int kq   = lane >> 4;        // 0..3

  f32x4 acc[4][4];
  #pragma unroll
  for (int i = 0; i < 4; ++i)
    #pragma unroll
    for (int j = 0; j < 4; ++j) {
      f32x4 z = {0.f, 0.f, 0.f, 0.f};
      acc[i][j] = z;
    }

  int Keff = K;
  if (CAUSAL_K) { int lim = m0 + BM; Keff = (K < lim) ? K : lim; }
  const int kTiles = Keff / BK;

  const int ar0 = tid >> 2;            // staging row
  const int ac0 = (tid & 3) << 3;      // staging col (8 elems = 16B)

  const unsigned short* A0 = A  + (size_t)(m0 + ar0)      * lda + ac0;
  const unsigned short* A1 = A  + (size_t)(m0 + 64 + ar0) * lda + ac0;
  const unsigned short* B0 = Bt + (size_t)(n0 + ar0)      * ldb + ac0;
  const unsigned short* B1 = Bt + (size_t)(n0 + 64 + ar0) * ldb + ac0;

  auto stage = [&](int buf, int kt) {
    const int k0 = kt * BK;
    gload_lds16(A0 + k0, &As[buf][wave * 512]);
    gload_lds16(A1 + k0, &As[buf][2048 + wave * 512]);
    gload_lds16(B0 + k0, &Bs[buf][wave * 512]);
    gload_lds16(B1 + k0, &Bs[buf][2048 + wave * 512]);
  };

  stage(0, 0);
  __syncthreads();            // drain prologue loads

  int cur = 0;
  for (int kt = 0; kt < kTiles; ++kt) {
    if (kt + 1 < kTiles) stage(cur ^ 1, kt + 1);   // issue BEFORE compute

    bf16x8 af[4], bfr[4];
    #pragma unroll
    for (int i = 0; i < 4; ++i) {
      af[i]  = *reinterpret_cast<const bf16x8*>(&As[cur][(wr * 64 + i * 16 + ln15) * BK + kq * 8]);
      bfr[i] = *reinterpret_cast<const bf16x8*>(&Bs[cur][(wc * 64 + i * 16 + ln15) * BK + kq * 8]);
    }
    #pragma unroll
    for (int i = 0; i < 4; ++i)
      #pragma unroll
      for (int j = 0; j < 4; ++j)
        acc[i][j] = __builtin_amdgcn_mfma_f32_16x16x32_bf16(af[i], bfr[j], acc[i][j], 0, 0, 0);

    __syncthreads();          // one barrier per K-step: drains prefetch + joins reads
    cur ^= 1;
  }

  // epilogue: C/D layout col = lane&15, row = (lane>>4)*4 + reg
  const int crow0 = m0 + wr * 64;
  const int ccol0 = n0 + wc * 64;
  float bvals[4] = {0.f, 0.f, 0.f, 0.f};
  if (OUT_MODE == 2) {
    #pragma unroll
    for (int j = 0; j < 4; ++j) bvals[j] = bias[ccol0 + j * 16 + ln15];
  }
  #pragma unroll
  for (int i = 0; i < 4; ++i) {
    const int r0 = crow0 + i * 16 + kq * 4;
    #pragma unroll
    for (int j = 0; j < 4; ++j) {
      const int c = ccol0 + j * 16 + ln15;
      #pragma unroll
      for (int rr = 0; rr < 4; ++rr) {
        const float vvv = acc[i][j][rr] + bvals[j];
        if (OUT_MODE == 1) {
          unsigned short* C = (unsigned short*)Cv + (long long)zb * sC;
          C[(size_t)(r0 + rr) * ldc + c] = f2bf(vvv);
        } else {
          float* C = (float*)Cv + (long long)zb * sC;
          C[(size_t)(r0 + rr) * ldc + c] = vvv;
        }
      }
    }
  }
}

// ---------- helpers ----------
__global__ __launch_bounds__(256) void cast_f32_bf16(
    const float* __restrict__ in, unsigned short* __restrict__ out, long long n) {
  long long i = ((long long)blockIdx.x * 256 + threadIdx.x) * 4;
  if (i + 4 <= n) {
    const float4 v = *reinterpret_cast<const float4*>(in + i);
    ushort4 o;
    o.x = f2bf(v.x); o.y = f2bf(v.y); o.z = f2bf(v.z); o.w = f2bf(v.w);
    *reinterpret_cast<ushort4*>(out + i) = o;
  } else {
    for (; i < n; ++i) out[i] = f2bf(in[i]);
  }
}

// WT[o][i] = bf16(W[i][o]); 32x32 tiles via LDS
__global__ void transcast_w(const float* __restrict__ W, unsigned short* __restrict__ WT,
                            int rows, int cols) {
  __shared__ float tile[32][33];
  const int c0 = blockIdx.x * 32, r0 = blockIdx.y * 32;
  const int tx = threadIdx.x, ty = threadIdx.y;
  #pragma unroll
  for (int r = ty; r < 32; r += 8)
    tile[r][tx] = W[(size_t)(r0 + r) * cols + (c0 + tx)];
  __syncthreads();
  #pragma unroll
  for (int r = ty; r < 32; r += 8)
    WT[(size_t)(c0 + r) * rows + (r0 + tx)] = f2bf(tile[tx][r]);
}

// per-batch bf16 transpose with input ld: VT[b][d][n] = V[b][n][d]
__global__ void trans_bf16(const unsigned short* __restrict__ V, unsigned short* __restrict__ VT,
                           int rows, int cols, int ld_in, long long sIn, long long sOut) {
  const size_t bi = (size_t)blockIdx.z * sIn;
  const size_t bo = (size_t)blockIdx.z * sOut;
  __shared__ unsigned short tile[32][33];
  const int c0 = blockIdx.x * 32, r0 = blockIdx.y * 32;
  const int tx = threadIdx.x, ty = threadIdx.y;
  #pragma unroll
  for (int r = ty; r < 32; r += 8)
    tile[r][tx] = V[bi + (size_t)(r0 + r) * ld_in + (c0 + tx)];
  __syncthreads();
  #pragma unroll
  for (int r = ty; r < 32; r += 8)
    VT[bo + (size_t)(c0 + r) * rows + (r0 + tx)] = tile[tx][r];
}

// causal row softmax: att[j] = softmax(S[0..r]*scale), zero-fill to 128 boundary
__global__ __launch_bounds__(256) void softmax_causal(
    const float* __restrict__ S, unsigned short* __restrict__ att, int N, float scale) {
  const int row = blockIdx.x;
  const int b = row / N;
  const int r = row - b * N;
  const float* s = S + (size_t)b * N * N + (size_t)r * N;
  unsigned short* a = att + (size_t)b * N * N + (size_t)r * N;
  const int L = r + 1;
  const int tid = threadIdx.x;
  __shared__ float red[4];

  float mx = -3.0e38f;
  for (int j = tid; j < L; j += 256) mx = fmaxf(mx, s[j]);
  #pragma unroll
  for (int o = 32; o > 0; o >>= 1) mx = fmaxf(mx, __shfl_xor(mx, o, 64));
  if ((tid & 63) == 0) red[tid >> 6] = mx;
  __syncthreads();
  mx = fmaxf(fmaxf(red[0], red[1]), fmaxf(red[2], red[3]));
  __syncthreads();

  float sum = 0.f;
  for (int j = tid; j < L; j += 256) sum += __expf((s[j] - mx) * scale);
  #pragma unroll
  for (int o = 32; o > 0; o >>= 1) sum += __shfl_xor(sum, o, 64);
  if ((tid & 63) == 0) red[tid >> 6] = sum;
  __syncthreads();
  sum = red[0] + red[1] + red[2] + red[3];
  const float inv = 1.f / sum;

  const int Lpad = (L + 127) & ~127;   // PV reads k < roundup(row+1,128)
  for (int j = tid; j < Lpad; j += 256) {
    const float p = (j < L) ? __expf((s[j] - mx) * scale) * inv : 0.f;
    a[j] = f2bf(p);
  }
}

// h = LN(attout + v) * gamma + beta  (D=1024, 256 thr x 4); v strided in fused QKV
__global__ __launch_bounds__(256) void add_layernorm(
    const unsigned short* __restrict__ ao, const unsigned short* __restrict__ qkv,
    int ldv, int voff,
    const float* __restrict__ gamma, const float* __restrict__ beta,
    unsigned short* __restrict__ h) {
  const size_t base  = (size_t)blockIdx.x * 1024;
  const size_t vbase = (size_t)blockIdx.x * ldv + voff;
  const int tid = threadIdx.x;
  float xv[4];
  float sum = 0.f, sq = 0.f;
  #pragma unroll
  for (int k = 0; k < 4; ++k) {
    const int j = tid + k * 256;
    const float t = bf2f(ao[base + j]) + bf2f(qkv[vbase + j]);
    xv[k] = t; sum += t; sq += t * t;
  }
  #pragma unroll
  for (int o = 32; o > 0; o >>= 1) { sum += __shfl_xor(sum, o, 64); sq += __shfl_xor(sq, o, 64); }
  __shared__ float rs_[4], rq_[4];
  if ((tid & 63) == 0) { rs_[tid >> 6] = sum; rq_[tid >> 6] = sq; }
  __syncthreads();
  sum = rs_[0] + rs_[1] + rs_[2] + rs_[3];
  sq  = rq_[0] + rq_[1] + rq_[2] + rq_[3];
  const float mu   = sum * (1.f / 1024.f);
  const float var  = sq * (1.f / 1024.f) - mu * mu;
  const float rstd = rsqrtf(var + 1e-5f);
  #pragma unroll
  for (int k = 0; k < 4; ++k) {
    const int j = tid + k * 256;
    h[base + j] = f2bf((xv[k] - mu) * rstd * gamma[j] + beta[j]);
  }
}

// ---------- launch ----------
extern "C" void kernel_launch(void* const* d_in, const int* in_sizes, int n_in,
                              void* d_out, int out_size, void* d_ws, size_t ws_size,
                              hipStream_t stream) {
  const float* x     = (const float*)d_in[0];
  const float* Wq    = (const float*)d_in[1];
  const float* Wk    = (const float*)d_in[2];
  const float* Wv    = (const float*)d_in[3];
  const float* Wfc   = (const float*)d_in[4];
  const float* bfc   = (const float*)d_in[5];
  const float* gamma = (const float*)d_in[6];
  const float* beta  = (const float*)d_in[7];
  float* out = (float*)d_out;

  const int Bn = 4, Nn = 2048, Dn = 1024;
  const int M = Bn * Nn;                       // 8192
  const int D3 = 3 * Dn;                       // 3072

  char* ws = (char*)d_ws;
  size_t off = 0;
  auto alloc = [&](size_t bytes) { void* p = ws + off; off += (bytes + 255) & ~255ULL; return p; };
  unsigned short* xb    = (unsigned short*)alloc((size_t)M * Dn * 2);        // 16 MB
  unsigned short* WqkvT = (unsigned short*)alloc((size_t)D3 * Dn * 2);       // 6 MB
  unsigned short* WfcT  = (unsigned short*)alloc((size_t)Dn * Dn * 2);       // 2 MB
  unsigned short* QKV   = (unsigned short*)alloc((size_t)M * D3 * 2);        // 48 MB
  unsigned short* VTb   = (unsigned short*)alloc((size_t)M * Dn * 2);        // 16 MB
  float*          S     = (float*)alloc((size_t)Bn * Nn * Nn * 4);           // 64 MB
  unsigned short* att   = (unsigned short*)alloc((size_t)Bn * Nn * Nn * 2);  // 32 MB
  // S is dead after softmax -> reuse its space for ao and h (16 MB each)
  unsigned short* ao = (unsigned short*)S;
  unsigned short* h  = (unsigned short*)S + (size_t)M * Dn;

  unsigned short* Qp = QKV;               // ld D3
  unsigned short* Kp = QKV + Dn;          // ld D3
  unsigned short* Vp = QKV + 2 * Dn;      // ld D3

  const dim3 blk(256);

  // 1. casts
  cast_f32_bf16<<<dim3(((long long)M * Dn) / 1024), blk, 0, stream>>>(x, xb, (long long)M * Dn);
  const dim3 tb(32, 8, 1), tg(Dn / 32, Dn / 32, 1);
  transcast_w<<<tg, tb, 0, stream>>>(Wq,  WqkvT,                        Dn, Dn);
  transcast_w<<<tg, tb, 0, stream>>>(Wk,  WqkvT + (size_t)Dn * Dn,     Dn, Dn);
  transcast_w<<<tg, tb, 0, stream>>>(Wv,  WqkvT + (size_t)2 * Dn * Dn, Dn, Dn);
  transcast_w<<<tg, tb, 0, stream>>>(Wfc, WfcT,                        Dn, Dn);

  // 2. fused QKV projection: [8192,1024] x [3072,1024]^T -> [8192,3072] bf16
  gemm_bt<1, false, false><<<dim3(D3 / BN, M / BM, 1), blk, 0, stream>>>(
      xb, WqkvT, QKV, nullptr, Dn, Dn, Dn, D3, 0, 0, 0);

  // 3. V^T for PV: VT[b][d][n]
  trans_bf16<<<dim3(Dn / 32, Nn / 32, Bn), tb, 0, stream>>>(
      Vp, VTb, Nn, Dn, D3, (long long)Nn * D3, (long long)Dn * Nn);

  // 4. scores = Q K^T (lower-triangle tiles only), fp32
  gemm_bt<0, true, false><<<dim3(Nn / BN, Nn / BM, Bn), blk, 0, stream>>>(
      Qp, Kp, S, nullptr, Dn, D3, D3, Nn,
      (long long)Nn * D3, (long long)Nn * D3, (long long)Nn * Nn);

  // 5. causal softmax -> bf16 att (zero-padded to tile boundary)
  softmax_causal<<<dim3(Bn * Nn), blk, 0, stream>>>(S, att, Nn, 0.03125f);

  // 6. attout = att @ V  (K limited to diagonal block)
  gemm_bt<1, false, true><<<dim3(Dn / BN, Nn / BM, Bn), blk, 0, stream>>>(
      att, VTb, ao, nullptr, Nn, Nn, Nn, Dn,
      (long long)Nn * Nn, (long long)Dn * Nn, (long long)Nn * Dn);

  // 7. h = LN(attout + v)
  add_layernorm<<<dim3(Bn * Nn), blk, 0, stream>>>(ao, QKV, D3, 2 * Dn, gamma, beta, h);

  // 8. out = h @ Wfc + bfc, fp32
  gemm_bt<2, false, false><<<dim3(Dn / BN, M / BM, 1), blk, 0, stream>>>(
      h, WfcT, out, bfc, Dn, Dn, Dn, Dn, 0, 0, 0);
}

// Round 6
// 319.758 us; speedup vs baseline: 1.2433x; 1.0631x over previous
//
#include <hip/hip_runtime.h>

// ---------- types ----------
typedef __bf16 bf16x8 __attribute__((ext_vector_type(8)));
typedef float  f32x4  __attribute__((ext_vector_type(4)));

__device__ __forceinline__ unsigned short f2bf(float f) {
  unsigned int u = __builtin_bit_cast(unsigned int, f);
  u = (u + 0x7FFFu + ((u >> 16) & 1u)) >> 16;   // RNE
  return (unsigned short)u;
}
__device__ __forceinline__ float bf2f(unsigned short h) {
  return __builtin_bit_cast(float, (unsigned int)h << 16);
}

// async global->LDS, 16B per lane; LDS base must be wave-uniform
__device__ __forceinline__ void gload_lds16(const void* g, void* l) {
  __builtin_amdgcn_global_load_lds(
      (__attribute__((address_space(1))) void*)(unsigned long long)g,
      (__attribute__((address_space(3))) void*)(unsigned int)(unsigned long long)l,
      16, 0, 0);
}

// ---------- GEMM: C = A[M,K] * Bt[N,K]^T ----------
// 128x128 tile, BK=32, 256 threads (4 waves, 2x2 wave grid, 64x64 per wave).
// 2-deep pipeline with counted vmcnt (T4): tiles t and t+1 in flight; per iter
// wait vmcnt(4) (tile t only), consume to regs, re-stage t+2 into freed buffer.
#define BM 128
#define BN 128
#define BK 32

// OUT_MODE: 0 = fp32, 1 = bf16, 2 = fp32 + bias
template<int OUT_MODE, bool CAUSAL_TRI, bool CAUSAL_K>
__global__ __launch_bounds__(256) void gemm_bt(
    const unsigned short* __restrict__ A, const unsigned short* __restrict__ Bt,
    void* __restrict__ Cv, const float* __restrict__ bias,
    int K, int lda, int ldb, int ldc,
    long long sA, long long sBt, long long sC)
{
  // bijective XCD swizzle (T1): requires gridDim.x*gridDim.y % 8 == 0 (true for
  // all our launches: 24x64, 16x16, 8x16, 8x64)
  int bx, by;
  {
    const int nwg = gridDim.x * gridDim.y;
    const int lin = blockIdx.y * gridDim.x + blockIdx.x;
    const int cpx = nwg >> 3;
    const int swz = (lin & 7) * cpx + (lin >> 3);
    bx = swz % gridDim.x;
    by = swz / gridDim.x;
  }
  const int m0 = by * BM;
  const int n0 = bx * BN;
  if (CAUSAL_TRI && n0 > m0) return;   // above-diagonal tile: never computed
  const int zb = blockIdx.z;
  A  += (long long)zb * sA;
  Bt += (long long)zb * sBt;

  __shared__ unsigned short As[2][BM * BK];   // 2 x 8 KB
  __shared__ unsigned short Bs[2][BN * BK];   // 2 x 8 KB

  const int tid  = threadIdx.x;
  const int wave = tid >> 6;
  const int lane = tid & 63;
  const int wr   = wave >> 1;        // wave row 0..1
  const int wc   = wave & 1;         // wave col 0..1
  const int ln15 = lane & 15;
  const int kq   = lane >> 4;        // 0..3

  f32x4 acc[4][4];
  #pragma unroll
  for (int i = 0; i < 4; ++i)
    #pragma unroll
    for (int j = 0; j < 4; ++j) {
      f32x4 z = {0.f, 0.f, 0.f, 0.f};
      acc[i][j] = z;
    }

  int Keff = K;
  if (CAUSAL_K) { int lim = m0 + BM; Keff = (K < lim) ? K : lim; }
  const int kTiles = Keff / BK;

  const int ar0 = tid >> 2;            // staging row
  const int ac0 = (tid & 3) << 3;      // staging col (8 elems = 16B)

  const unsigned short* A0 = A  + (size_t)(m0 + ar0)      * lda + ac0;
  const unsigned short* A1 = A  + (size_t)(m0 + 64 + ar0) * lda + ac0;
  const unsigned short* B0 = Bt + (size_t)(n0 + ar0)      * ldb + ac0;
  const unsigned short* B1 = Bt + (size_t)(n0 + 64 + ar0) * ldb + ac0;

  auto stage = [&](int buf, int kt) {
    const int k0 = kt * BK;
    gload_lds16(A0 + k0, &As[buf][wave * 512]);
    gload_lds16(A1 + k0, &As[buf][2048 + wave * 512]);
    gload_lds16(B0 + k0, &Bs[buf][wave * 512]);
    gload_lds16(B1 + k0, &Bs[buf][2048 + wave * 512]);
  };

  // prologue: tiles 0 and 1 in flight
  stage(0, 0);
  if (kTiles > 1) stage(1, 1);

  for (int kt = 0; kt < kTiles; ++kt) {
    const int cur = kt & 1;

    // wait for the CURRENT tile's 4 loads only (newer tile stays in flight)
    if (kt < kTiles - 1) asm volatile("s_waitcnt vmcnt(4)" ::: "memory");
    else                 asm volatile("s_waitcnt vmcnt(0)" ::: "memory");
    __builtin_amdgcn_sched_barrier(0);
    __builtin_amdgcn_s_barrier();           // all waves: cur tile resident in LDS
    __builtin_amdgcn_sched_barrier(0);

    bf16x8 af[4], bfr[4];
    #pragma unroll
    for (int i = 0; i < 4; ++i) {
      af[i]  = *reinterpret_cast<const bf16x8*>(&As[cur][(wr * 64 + i * 16 + ln15) * BK + kq * 8]);
      bfr[i] = *reinterpret_cast<const bf16x8*>(&Bs[cur][(wc * 64 + i * 16 + ln15) * BK + kq * 8]);
    }
    __builtin_amdgcn_sched_barrier(0);
    asm volatile("s_waitcnt lgkmcnt(0)" ::: "memory");   // frags in regs
    __builtin_amdgcn_sched_barrier(0);
    __builtin_amdgcn_s_barrier();           // all waves: cur consumed -> safe to overwrite
    __builtin_amdgcn_sched_barrier(0);

    if (kt + 2 < kTiles) stage(cur, kt + 2);   // refill freed buffer

    #pragma unroll
    for (int i = 0; i < 4; ++i)
      #pragma unroll
      for (int j = 0; j < 4; ++j)
        acc[i][j] = __builtin_amdgcn_mfma_f32_16x16x32_bf16(af[i], bfr[j], acc[i][j], 0, 0, 0);
  }

  // epilogue: C/D layout col = lane&15, row = (lane>>4)*4 + reg
  const int crow0 = m0 + wr * 64;
  const int ccol0 = n0 + wc * 64;
  float bvals[4] = {0.f, 0.f, 0.f, 0.f};
  if (OUT_MODE == 2) {
    #pragma unroll
    for (int j = 0; j < 4; ++j) bvals[j] = bias[ccol0 + j * 16 + ln15];
  }
  #pragma unroll
  for (int i = 0; i < 4; ++i) {
    const int r0 = crow0 + i * 16 + kq * 4;
    #pragma unroll
    for (int j = 0; j < 4; ++j) {
      const int c = ccol0 + j * 16 + ln15;
      #pragma unroll
      for (int rr = 0; rr < 4; ++rr) {
        const float vvv = acc[i][j][rr] + bvals[j];
        if (OUT_MODE == 1) {
          unsigned short* C = (unsigned short*)Cv + (long long)zb * sC;
          C[(size_t)(r0 + rr) * ldc + c] = f2bf(vvv);
        } else {
          float* C = (float*)Cv + (long long)zb * sC;
          C[(size_t)(r0 + rr) * ldc + c] = vvv;
        }
      }
    }
  }
}

// ---------- helpers ----------
__global__ __launch_bounds__(256) void cast_f32_bf16(
    const float* __restrict__ in, unsigned short* __restrict__ out, long long n) {
  long long i = ((long long)blockIdx.x * 256 + threadIdx.x) * 4;
  if (i + 4 <= n) {
    const float4 v = *reinterpret_cast<const float4*>(in + i);
    ushort4 o;
    o.x = f2bf(v.x); o.y = f2bf(v.y); o.z = f2bf(v.z); o.w = f2bf(v.w);
    *reinterpret_cast<ushort4*>(out + i) = o;
  } else {
    for (; i < n; ++i) out[i] = f2bf(in[i]);
  }
}

// WT[o][i] = bf16(W[i][o]); 32x32 tiles via LDS; z selects one of 4 weights
__global__ void transcast_w4(
    const float* __restrict__ W0, const float* __restrict__ W1,
    const float* __restrict__ W2, const float* __restrict__ W3,
    unsigned short* __restrict__ T0, unsigned short* __restrict__ T1,
    unsigned short* __restrict__ T2, unsigned short* __restrict__ T3,
    int rows, int cols) {
  const int z = blockIdx.z;
  const float* W = (z == 0) ? W0 : (z == 1) ? W1 : (z == 2) ? W2 : W3;
  unsigned short* WT = (z == 0) ? T0 : (z == 1) ? T1 : (z == 2) ? T2 : T3;
  __shared__ float tile[32][33];
  const int c0 = blockIdx.x * 32, r0 = blockIdx.y * 32;
  const int tx = threadIdx.x, ty = threadIdx.y;
  #pragma unroll
  for (int r = ty; r < 32; r += 8)
    tile[r][tx] = W[(size_t)(r0 + r) * cols + (c0 + tx)];
  __syncthreads();
  #pragma unroll
  for (int r = ty; r < 32; r += 8)
    WT[(size_t)(c0 + r) * rows + (r0 + tx)] = f2bf(tile[tx][r]);
}

// per-batch bf16 transpose with input ld: VT[b][d][n] = V[b][n][d]
__global__ void trans_bf16(const unsigned short* __restrict__ V, unsigned short* __restrict__ VT,
                           int rows, int cols, int ld_in, long long sIn, long long sOut) {
  const size_t bi = (size_t)blockIdx.z * sIn;
  const size_t bo = (size_t)blockIdx.z * sOut;
  __shared__ unsigned short tile[32][33];
  const int c0 = blockIdx.x * 32, r0 = blockIdx.y * 32;
  const int tx = threadIdx.x, ty = threadIdx.y;
  #pragma unroll
  for (int r = ty; r < 32; r += 8)
    tile[r][tx] = V[bi + (size_t)(r0 + r) * ld_in + (c0 + tx)];
  __syncthreads();
  #pragma unroll
  for (int r = ty; r < 32; r += 8)
    VT[bo + (size_t)(c0 + r) * rows + (r0 + tx)] = tile[tx][r];
}

// causal row softmax, single-pass: row (N=2048 fp32) lives in registers
// (8 floats/thread). att[j] = softmax(S[0..r]*scale), zero-fill to 128 boundary.
__global__ __launch_bounds__(256) void softmax_causal(
    const float* __restrict__ S, unsigned short* __restrict__ att, int N, float scale) {
  const int row = blockIdx.x;
  const int b = row / N;
  const int r = row - b * N;
  const float* s = S + (size_t)b * N * N + (size_t)r * N;
  unsigned short* a = att + (size_t)b * N * N + (size_t)r * N;
  const int L = r + 1;
  const int Lpad = (L + 127) & ~127;   // PV reads k < roundup(row+1,128)
  const int tid = threadIdx.x;
  const int j0 = tid * 8;
  const bool active = j0 < Lpad;       // S[j] is computed (finite) for all j < Lpad

  float v[8];
  if (active) {
    const float4 p0 = *reinterpret_cast<const float4*>(s + j0);
    const float4 p1 = *reinterpret_cast<const float4*>(s + j0 + 4);
    v[0] = p0.x; v[1] = p0.y; v[2] = p0.z; v[3] = p0.w;
    v[4] = p1.x; v[5] = p1.y; v[6] = p1.z; v[7] = p1.w;
  }

  __shared__ float redm[4], reds[4];

  float mx = -3.0e38f;
  if (active) {
    #pragma unroll
    for (int k = 0; k < 8; ++k) mx = fmaxf(mx, (j0 + k < L) ? v[k] : -3.0e38f);
  }
  #pragma unroll
  for (int o = 32; o > 0; o >>= 1) mx = fmaxf(mx, __shfl_xor(mx, o, 64));
  if ((tid & 63) == 0) redm[tid >> 6] = mx;
  __syncthreads();
  mx = fmaxf(fmaxf(redm[0], redm[1]), fmaxf(redm[2], redm[3]));

  float e[8];
  float sum = 0.f;
  if (active) {
    #pragma unroll
    for (int k = 0; k < 8; ++k) {
      e[k] = (j0 + k < L) ? __expf((v[k] - mx) * scale) : 0.f;
      sum += e[k];
    }
  }
  #pragma unroll
  for (int o = 32; o > 0; o >>= 1) sum += __shfl_xor(sum, o, 64);
  if ((tid & 63) == 0) reds[tid >> 6] = sum;
  __syncthreads();
  sum = reds[0] + reds[1] + reds[2] + reds[3];
  const float inv = 1.f / sum;

  if (active) {
    uint4 w;
    unsigned int t0 = f2bf(e[0] * inv), t1 = f2bf(e[1] * inv);
    unsigned int t2 = f2bf(e[2] * inv), t3 = f2bf(e[3] * inv);
    unsigned int t4 = f2bf(e[4] * inv), t5 = f2bf(e[5] * inv);
    unsigned int t6 = f2bf(e[6] * inv), t7 = f2bf(e[7] * inv);
    w.x = t0 | (t1 << 16); w.y = t2 | (t3 << 16);
    w.z = t4 | (t5 << 16); w.w = t6 | (t7 << 16);
    *reinterpret_cast<uint4*>(a + j0) = w;
  }
}

// h = LN(attout + v) * gamma + beta  (D=1024, 256 thr x 4 contiguous)
__global__ __launch_bounds__(256) void add_layernorm(
    const unsigned short* __restrict__ ao, const unsigned short* __restrict__ qkv,
    int ldv, int voff,
    const float* __restrict__ gamma, const float* __restrict__ beta,
    unsigned short* __restrict__ h) {
  const size_t base  = (size_t)blockIdx.x * 1024;
  const size_t vbase = (size_t)blockIdx.x * ldv + voff;
  const int tid = threadIdx.x;
  const int j = tid * 4;

  const ushort4 a4 = *reinterpret_cast<const ushort4*>(ao + base + j);
  const ushort4 v4 = *reinterpret_cast<const ushort4*>(qkv + vbase + j);
  float xv[4];
  xv[0] = bf2f(a4.x) + bf2f(v4.x);
  xv[1] = bf2f(a4.y) + bf2f(v4.y);
  xv[2] = bf2f(a4.z) + bf2f(v4.z);
  xv[3] = bf2f(a4.w) + bf2f(v4.w);
  float sum = xv[0] + xv[1] + xv[2] + xv[3];
  float sq  = xv[0]*xv[0] + xv[1]*xv[1] + xv[2]*xv[2] + xv[3]*xv[3];

  #pragma unroll
  for (int o = 32; o > 0; o >>= 1) { sum += __shfl_xor(sum, o, 64); sq += __shfl_xor(sq, o, 64); }
  __shared__ float rs_[4], rq_[4];
  if ((tid & 63) == 0) { rs_[tid >> 6] = sum; rq_[tid >> 6] = sq; }
  __syncthreads();
  sum = rs_[0] + rs_[1] + rs_[2] + rs_[3];
  sq  = rq_[0] + rq_[1] + rq_[2] + rq_[3];
  const float mu   = sum * (1.f / 1024.f);
  const float var  = sq * (1.f / 1024.f) - mu * mu;
  const float rstd = rsqrtf(var + 1e-5f);

  const float4 g4 = *reinterpret_cast<const float4*>(gamma + j);
  const float4 b4 = *reinterpret_cast<const float4*>(beta + j);
  ushort4 o4;
  o4.x = f2bf((xv[0] - mu) * rstd * g4.x + b4.x);
  o4.y = f2bf((xv[1] - mu) * rstd * g4.y + b4.y);
  o4.z = f2bf((xv[2] - mu) * rstd * g4.z + b4.z);
  o4.w = f2bf((xv[3] - mu) * rstd * g4.w + b4.w);
  *reinterpret_cast<ushort4*>(h + base + j) = o4;
}

// ---------- launch ----------
extern "C" void kernel_launch(void* const* d_in, const int* in_sizes, int n_in,
                              void* d_out, int out_size, void* d_ws, size_t ws_size,
                              hipStream_t stream) {
  const float* x     = (const float*)d_in[0];
  const float* Wq    = (const float*)d_in[1];
  const float* Wk    = (const float*)d_in[2];
  const float* Wv    = (const float*)d_in[3];
  const float* Wfc   = (const float*)d_in[4];
  const float* bfc   = (const float*)d_in[5];
  const float* gamma = (const float*)d_in[6];
  const float* beta  = (const float*)d_in[7];
  float* out = (float*)d_out;

  const int Bn = 4, Nn = 2048, Dn = 1024;
  const int M = Bn * Nn;                       // 8192
  const int D3 = 3 * Dn;                       // 3072

  char* ws = (char*)d_ws;
  size_t off = 0;
  auto alloc = [&](size_t bytes) { void* p = ws + off; off += (bytes + 255) & ~255ULL; return p; };
  unsigned short* xb    = (unsigned short*)alloc((size_t)M * Dn * 2);        // 16 MB
  unsigned short* WqkvT = (unsigned short*)alloc((size_t)D3 * Dn * 2);       // 6 MB
  unsigned short* WfcT  = (unsigned short*)alloc((size_t)Dn * Dn * 2);       // 2 MB
  unsigned short* QKV   = (unsigned short*)alloc((size_t)M * D3 * 2);        // 48 MB
  unsigned short* VTb   = (unsigned short*)alloc((size_t)M * Dn * 2);        // 16 MB
  float*          S     = (float*)alloc((size_t)Bn * Nn * Nn * 4);           // 64 MB
  unsigned short* att   = (unsigned short*)alloc((size_t)Bn * Nn * Nn * 2);  // 32 MB
  // S is dead after softmax -> reuse its space for ao and h (16 MB each)
  unsigned short* ao = (unsigned short*)S;
  unsigned short* h  = (unsigned short*)S + (size_t)M * Dn;

  unsigned short* Qp = QKV;               // ld D3
  unsigned short* Kp = QKV + Dn;          // ld D3
  unsigned short* Vp = QKV + 2 * Dn;      // ld D3

  const dim3 blk(256);

  // 1. casts
  cast_f32_bf16<<<dim3(((long long)M * Dn) / 1024), blk, 0, stream>>>(x, xb, (long long)M * Dn);
  const dim3 tb(32, 8, 1);
  transcast_w4<<<dim3(Dn / 32, Dn / 32, 4), tb, 0, stream>>>(
      Wq, Wk, Wv, Wfc,
      WqkvT, WqkvT + (size_t)Dn * Dn, WqkvT + (size_t)2 * Dn * Dn, WfcT, Dn, Dn);

  // 2. fused QKV projection: [8192,1024] x [3072,1024]^T -> [8192,3072] bf16
  gemm_bt<1, false, false><<<dim3(D3 / BN, M / BM, 1), blk, 0, stream>>>(
      xb, WqkvT, QKV, nullptr, Dn, Dn, Dn, D3, 0, 0, 0);

  // 3. V^T for PV: VT[b][d][n]
  trans_bf16<<<dim3(Dn / 32, Nn / 32, Bn), tb, 0, stream>>>(
      Vp, VTb, Nn, Dn, D3, (long long)Nn * D3, (long long)Dn * Nn);

  // 4. scores = Q K^T (lower-triangle tiles only), fp32
  gemm_bt<0, true, false><<<dim3(Nn / BN, Nn / BM, Bn), blk, 0, stream>>>(
      Qp, Kp, S, nullptr, Dn, D3, D3, Nn,
      (long long)Nn * D3, (long long)Nn * D3, (long long)Nn * Nn);

  // 5. causal softmax -> bf16 att (zero-padded to tile boundary)
  softmax_causal<<<dim3(Bn * Nn), blk, 0, stream>>>(S, att, Nn, 0.03125f);

  // 6. attout = att @ V  (K limited to diagonal block)
  gemm_bt<1, false, true><<<dim3(Dn / BN, Nn / BM, Bn), blk, 0, stream>>>(
      att, VTb, ao, nullptr, Nn, Nn, Nn, Dn,
      (long long)Nn * Nn, (long long)Dn * Nn, (long long)Nn * Dn);

  // 7. h = LN(attout + v)
  add_layernorm<<<dim3(Bn * Nn), blk, 0, stream>>>(ao, QKV, D3, 2 * Dn, gamma, beta, h);

  // 8. out = h @ Wfc + bfc, fp32
  gemm_bt<2, false, false><<<dim3(Dn / BN, M / BM, 1), blk, 0, stream>>>(
      h, WfcT, out, bfc, Dn, Dn, Dn, Dn, 0, 0, 0);
}

// Round 9
// 318.557 us; speedup vs baseline: 1.2480x; 1.0038x over previous
//
#include <hip/hip_runtime.h>

// ---------- types ----------
typedef __bf16 bf16x8 __attribute__((ext_vector_type(8)));
typedef float  f32x4  __attribute__((ext_vector_type(4)));

__device__ __forceinline__ unsigned short f2bf(float f) {
  unsigned int u = __builtin_bit_cast(unsigned int, f);
  u = (u + 0x7FFFu + ((u >> 16) & 1u)) >> 16;   // RNE
  return (unsigned short)u;
}
__device__ __forceinline__ float bf2f(unsigned short h) {
  return __builtin_bit_cast(float, (unsigned int)h << 16);
}

// async global->LDS, 16B per lane; LDS base must be wave-uniform
__device__ __forceinline__ void gload_lds16(const void* g, void* l) {
  __builtin_amdgcn_global_load_lds(
      (__attribute__((address_space(1))) void*)(unsigned long long)g,
      (__attribute__((address_space(3))) void*)(unsigned int)(unsigned long long)l,
      16, 0, 0);
}

// ============================================================================
// gemm8_bt: C = A[M,K] * Bt[N,K]^T, 256x256 tile, BK=32, 512 thr (8 waves 2Mx4N)
// Phased schedule: ring of 4 K-tile LDS buffers (128 KB), 2 phases/K-tile,
// counted vmcnt(8) (T4), XOR-swizzled LDS (T2), setprio around MFMA (T5).
// Staging for K-tile kt+3 goes into the slot freed at the end of kt-1; it is
// issued only after the barrier that follows kt-1's lgkmcnt(0), so no wave can
// still have unserviced ds_reads of the old contents.  Reads of tile kt+1 are
// covered by the tile-end vmcnt (everything older than the 8 newest loads has
// landed) + s_barrier.
// ============================================================================
#define BM8 256
#define BN8 256
#define BK8 32

// OUT_MODE: 0 = fp32, 1 = bf16, 2 = fp32 + bias
template<int OUT_MODE, bool CAUSAL_TRI>
__global__ __launch_bounds__(512, 2) void gemm8_bt(
    const unsigned short* __restrict__ A, const unsigned short* __restrict__ Bt,
    void* __restrict__ Cv, const float* __restrict__ bias,
    int K, int lda, int ldb, int ldc,
    long long sA, long long sBt, long long sC)
{
  // bijective XCD swizzle (T1); all grids have nwg % 8 == 0
  int bx, by;
  {
    const int nwg = gridDim.x * gridDim.y;
    const int lin = blockIdx.y * gridDim.x + blockIdx.x;
    const int cpx = nwg >> 3;
    const int swz = (lin & 7) * cpx + (lin >> 3);
    bx = swz % gridDim.x;
    by = swz / gridDim.x;
  }
  const int m0 = by * BM8;
  const int n0 = bx * BN8;
  if (CAUSAL_TRI && n0 > m0) return;     // block-uniform, before any barrier
  const int zb = blockIdx.z;
  A  += (long long)zb * sA;
  Bt += (long long)zb * sBt;

  // 4 bufs x (A-tile 16KB + B-tile 16KB) = 128 KB.
  // Per tile: A half h (rows h*128..h*128+127) at byte h*8192; B at +16384.
  // Half layout: 64 LDS-rows x 128B; LDS-row l holds global rows (2l, 2l+1)
  // (32 cols each = 4x16B blocks); 16B block b stored at b ^ (l & 7).
  __shared__ unsigned short lds[4 * 16384];

  const int tid  = threadIdx.x;          // 0..511
  const int wave = tid >> 6;
  const int lane = tid & 63;
  const int wr   = wave >> 2;            // 0..1  (M half)
  const int wc   = wave & 3;             // 0..3  (N quarter)
  const int ln15 = lane & 15;
  const int kq   = lane >> 4;            // 0..3
  const int lrow2 = ln15 >> 1;
  // per-lane swizzled offset within a 1KB fragment group (ushort units):
  // row pair l = lrow2, block = (odd*4 + kq) ^ lrow2
  const int ldsLaneU = (lrow2 * 128 + (((((ln15 & 1) << 2) + kq) ^ lrow2) << 4)) >> 1;

  // staging source mapping (rule #21: linear LDS dest + inverse-swizzled src)
  const int l8   = tid >> 3;                    // LDS-row this thread fills
  const int blk  = (tid & 7) ^ (l8 & 7);        // global 16B block it must hold
  const int srow = (l8 << 1) + (blk >> 2);      // global row within half (0..127)
  const int scol = (blk & 3) << 3;              // global col (elements)
  const unsigned short* Asrc = A  + (size_t)(m0 + srow) * lda + scol;
  const unsigned short* Bsrc = Bt + (size_t)(n0 + srow) * ldb + scol;
  const int ldsWave = wave * 512;               // ushort (1 KB per wave)

  f32x4 acc[8][4];
  #pragma unroll
  for (int i = 0; i < 8; ++i)
    #pragma unroll
    for (int j = 0; j < 4; ++j) {
      f32x4 z = {0.f, 0.f, 0.f, 0.f};
      acc[i][j] = z;
    }

  const int KT = K / BK8;

  auto stageHalfA = [&](int kt, int h) {
    gload_lds16(Asrc + (size_t)h * 128 * lda + kt * BK8,
                &lds[(kt & 3) * 16384 + h * 4096 + ldsWave]);
  };
  auto stageHalfB = [&](int kt, int h) {
    gload_lds16(Bsrc + (size_t)h * 128 * ldb + kt * BK8,
                &lds[(kt & 3) * 16384 + 8192 + h * 4096 + ldsWave]);
  };

  // prologue: stage tiles 0,1,2 (12 loads); wait so tile 0 is resident
  const int npro = (KT < 3) ? KT : 3;
  for (int j = 0; j < npro; ++j) {
    stageHalfA(j, 0); stageHalfA(j, 1); stageHalfB(j, 0); stageHalfB(j, 1);
  }
  if (npro >= 3) asm volatile("s_waitcnt vmcnt(8)" ::: "memory");
  else           asm volatile("s_waitcnt vmcnt(0)" ::: "memory");
  __builtin_amdgcn_s_barrier();
  __builtin_amdgcn_sched_barrier(0);

  const int aOff = wr * 4096;                                  // ushort
  const int bOff = 8192 + (wc >> 1) * 4096 + (wc & 1) * 2048;  // ushort

  for (int kt = 0; kt < KT; ++kt) {
    const int bufU = (kt & 3) * 16384;
    const bool doSt = (kt + 3) < KT;

    // ---- phase 0: stage A(kt+3); read b0..3 + a0..3; MFMA fm 0..3 ----
    if (doSt) { stageHalfA(kt + 3, 0); stageHalfA(kt + 3, 1); }
    bf16x8 bfrag[4], af[4];
    #pragma unroll
    for (int fn = 0; fn < 4; ++fn)
      bfrag[fn] = *reinterpret_cast<const bf16x8*>(&lds[bufU + bOff + fn * 512 + ldsLaneU]);
    #pragma unroll
    for (int fm = 0; fm < 4; ++fm)
      af[fm] = *reinterpret_cast<const bf16x8*>(&lds[bufU + aOff + fm * 512 + ldsLaneU]);
    asm volatile("s_waitcnt lgkmcnt(0)" ::: "memory");  // own reads serviced
    __builtin_amdgcn_s_barrier();
    __builtin_amdgcn_sched_barrier(0);
    __builtin_amdgcn_s_setprio(1);
    #pragma unroll
    for (int fm = 0; fm < 4; ++fm)
      #pragma unroll
      for (int fn = 0; fn < 4; ++fn)
        acc[fm][fn] = __builtin_amdgcn_mfma_f32_16x16x32_bf16(af[fm], bfrag[fn], acc[fm][fn], 0, 0, 0);
    __builtin_amdgcn_s_setprio(0);

    // ---- phase 1: stage B(kt+3); read a4..7; tile-end wait; MFMA fm 4..7 ----
    if (doSt) { stageHalfB(kt + 3, 0); stageHalfB(kt + 3, 1); }
    bf16x8 af2[4];
    #pragma unroll
    for (int fm = 0; fm < 4; ++fm)
      af2[fm] = *reinterpret_cast<const bf16x8*>(&lds[bufU + aOff + (4 + fm) * 512 + ldsLaneU]);
    asm volatile("s_waitcnt lgkmcnt(0)" ::: "memory");
    // counted tile-end wait: tiles <= kt+1 must be resident after the barrier;
    // outstanding allowed = stagings for kt+2 (4) + kt+3 (4) where they exist
    if (kt < KT - 3)       asm volatile("s_waitcnt vmcnt(8)" ::: "memory");
    else if (kt == KT - 3) asm volatile("s_waitcnt vmcnt(4)" ::: "memory");
    else                   asm volatile("s_waitcnt vmcnt(0)" ::: "memory");
    __builtin_amdgcn_s_barrier();
    __builtin_amdgcn_sched_barrier(0);
    __builtin_amdgcn_s_setprio(1);
    #pragma unroll
    for (int fm = 0; fm < 4; ++fm)
      #pragma unroll
      for (int fn = 0; fn < 4; ++fn)
        acc[4 + fm][fn] = __builtin_amdgcn_mfma_f32_16x16x32_bf16(af2[fm], bfrag[fn], acc[4 + fm][fn], 0, 0, 0);
    __builtin_amdgcn_s_setprio(0);
  }

  // epilogue: C/D layout col = lane&15, row = (lane>>4)*4 + reg
  const int crow0 = m0 + wr * 128;
  const int ccol0 = n0 + wc * 64;
  float bvals[4] = {0.f, 0.f, 0.f, 0.f};
  if (OUT_MODE == 2) {
    #pragma unroll
    for (int fn = 0; fn < 4; ++fn) bvals[fn] = bias[ccol0 + fn * 16 + ln15];
  }
  #pragma unroll
  for (int fm = 0; fm < 8; ++fm) {
    const int r0 = crow0 + fm * 16 + kq * 4;
    #pragma unroll
    for (int fn = 0; fn < 4; ++fn) {
      const int c = ccol0 + fn * 16 + ln15;
      #pragma unroll
      for (int rr = 0; rr < 4; ++rr) {
        const float vvv = acc[fm][fn][rr] + bvals[fn];
        if (OUT_MODE == 1) {
          unsigned short* C = (unsigned short*)Cv + (long long)zb * sC;
          C[(size_t)(r0 + rr) * ldc + c] = f2bf(vvv);
        } else {
          float* C = (float*)Cv + (long long)zb * sC;
          C[(size_t)(r0 + rr) * ldc + c] = vvv;
        }
      }
    }
  }
}

// ============================================================================
// gemm_bt: 128x128 2-deep counted-vmcnt kernel (kept for PV: balanced 512-block
// grid + variable causal K; a 256 tile would be 128 blocks w/ 2048-deep tail)
// ============================================================================
#define BM 128
#define BN 128
#define BK 32

template<int OUT_MODE, bool CAUSAL_TRI, bool CAUSAL_K>
__global__ __launch_bounds__(256) void gemm_bt(
    const unsigned short* __restrict__ A, const unsigned short* __restrict__ Bt,
    void* __restrict__ Cv, const float* __restrict__ bias,
    int K, int lda, int ldb, int ldc,
    long long sA, long long sBt, long long sC)
{
  int bx, by;
  {
    const int nwg = gridDim.x * gridDim.y;
    const int lin = blockIdx.y * gridDim.x + blockIdx.x;
    const int cpx = nwg >> 3;
    const int swz = (lin & 7) * cpx + (lin >> 3);
    bx = swz % gridDim.x;
    by = swz / gridDim.x;
  }
  const int m0 = by * BM;
  const int n0 = bx * BN;
  if (CAUSAL_TRI && n0 > m0) return;
  const int zb = blockIdx.z;
  A  += (long long)zb * sA;
  Bt += (long long)zb * sBt;

  __shared__ unsigned short As[2][BM * BK];
  __shared__ unsigned short Bs[2][BN * BK];

  const int tid  = threadIdx.x;
  const int wave = tid >> 6;
  const int lane = tid & 63;
  const int wr   = wave >> 1;
  const int wc   = wave & 1;
  const int ln15 = lane & 15;
  const int kq   = lane >> 4;

  f32x4 acc[4][4];
  #pragma unroll
  for (int i = 0; i < 4; ++i)
    #pragma unroll
    for (int j = 0; j < 4; ++j) {
      f32x4 z = {0.f, 0.f, 0.f, 0.f};
      acc[i][j] = z;
    }

  int Keff = K;
  if (CAUSAL_K) { int lim = m0 + BM; Keff = (K < lim) ? K : lim; }
  const int kTiles = Keff / BK;

  const int ar0 = tid >> 2;
  const int ac0 = (tid & 3) << 3;

  const unsigned short* A0 = A  + (size_t)(m0 + ar0)      * lda + ac0;
  const unsigned short* A1 = A  + (size_t)(m0 + 64 + ar0) * lda + ac0;
  const unsigned short* B0 = Bt + (size_t)(n0 + ar0)      * ldb + ac0;
  const unsigned short* B1 = Bt + (size_t)(n0 + 64 + ar0) * ldb + ac0;

  auto stage = [&](int buf, int kt) {
    const int k0 = kt * BK;
    gload_lds16(A0 + k0, &As[buf][wave * 512]);
    gload_lds16(A1 + k0, &As[buf][2048 + wave * 512]);
    gload_lds16(B0 + k0, &Bs[buf][wave * 512]);
    gload_lds16(B1 + k0, &Bs[buf][2048 + wave * 512]);
  };

  stage(0, 0);
  if (kTiles > 1) stage(1, 1);

  for (int kt = 0; kt < kTiles; ++kt) {
    const int cur = kt & 1;
    if (kt < kTiles - 1) asm volatile("s_waitcnt vmcnt(4)" ::: "memory");
    else                 asm volatile("s_waitcnt vmcnt(0)" ::: "memory");
    __builtin_amdgcn_sched_barrier(0);
    __builtin_amdgcn_s_barrier();
    __builtin_amdgcn_sched_barrier(0);

    bf16x8 af[4], bfr[4];
    #pragma unroll
    for (int i = 0; i < 4; ++i) {
      af[i]  = *reinterpret_cast<const bf16x8*>(&As[cur][(wr * 64 + i * 16 + ln15) * BK + kq * 8]);
      bfr[i] = *reinterpret_cast<const bf16x8*>(&Bs[cur][(wc * 64 + i * 16 + ln15) * BK + kq * 8]);
    }
    __builtin_amdgcn_sched_barrier(0);
    asm volatile("s_waitcnt lgkmcnt(0)" ::: "memory");
    __builtin_amdgcn_sched_barrier(0);
    __builtin_amdgcn_s_barrier();
    __builtin_amdgcn_sched_barrier(0);

    if (kt + 2 < kTiles) stage(cur, kt + 2);

    #pragma unroll
    for (int i = 0; i < 4; ++i)
      #pragma unroll
      for (int j = 0; j < 4; ++j)
        acc[i][j] = __builtin_amdgcn_mfma_f32_16x16x32_bf16(af[i], bfr[j], acc[i][j], 0, 0, 0);
  }

  const int crow0 = m0 + wr * 64;
  const int ccol0 = n0 + wc * 64;
  float bvals[4] = {0.f, 0.f, 0.f, 0.f};
  if (OUT_MODE == 2) {
    #pragma unroll
    for (int j = 0; j < 4; ++j) bvals[j] = bias[ccol0 + j * 16 + ln15];
  }
  #pragma unroll
  for (int i = 0; i < 4; ++i) {
    const int r0 = crow0 + i * 16 + kq * 4;
    #pragma unroll
    for (int j = 0; j < 4; ++j) {
      const int c = ccol0 + j * 16 + ln15;
      #pragma unroll
      for (int rr = 0; rr < 4; ++rr) {
        const float vvv = acc[i][j][rr] + bvals[j];
        if (OUT_MODE == 1) {
          unsigned short* C = (unsigned short*)Cv + (long long)zb * sC;
          C[(size_t)(r0 + rr) * ldc + c] = f2bf(vvv);
        } else {
          float* C = (float*)Cv + (long long)zb * sC;
          C[(size_t)(r0 + rr) * ldc + c] = vvv;
        }
      }
    }
  }
}

// ---------- helpers ----------
__global__ __launch_bounds__(256) void cast_f32_bf16(
    const float* __restrict__ in, unsigned short* __restrict__ out, long long n) {
  long long i = ((long long)blockIdx.x * 256 + threadIdx.x) * 4;
  if (i + 4 <= n) {
    const float4 v = *reinterpret_cast<const float4*>(in + i);
    ushort4 o;
    o.x = f2bf(v.x); o.y = f2bf(v.y); o.z = f2bf(v.z); o.w = f2bf(v.w);
    *reinterpret_cast<ushort4*>(out + i) = o;
  } else {
    for (; i < n; ++i) out[i] = f2bf(in[i]);
  }
}

// WT[o][i] = bf16(W[i][o]); 32x32 tiles via LDS; z selects one of 4 weights
__global__ void transcast_w4(
    const float* __restrict__ W0, const float* __restrict__ W1,
    const float* __restrict__ W2, const float* __restrict__ W3,
    unsigned short* __restrict__ T0, unsigned short* __restrict__ T1,
    unsigned short* __restrict__ T2, unsigned short* __restrict__ T3,
    int rows, int cols) {
  const int z = blockIdx.z;
  const float* W = (z == 0) ? W0 : (z == 1) ? W1 : (z == 2) ? W2 : W3;
  unsigned short* WT = (z == 0) ? T0 : (z == 1) ? T1 : (z == 2) ? T2 : T3;
  __shared__ float tile[32][33];
  const int c0 = blockIdx.x * 32, r0 = blockIdx.y * 32;
  const int tx = threadIdx.x, ty = threadIdx.y;
  #pragma unroll
  for (int r = ty; r < 32; r += 8)
    tile[r][tx] = W[(size_t)(r0 + r) * cols + (c0 + tx)];
  __syncthreads();
  #pragma unroll
  for (int r = ty; r < 32; r += 8)
    WT[(size_t)(c0 + r) * rows + (r0 + tx)] = f2bf(tile[tx][r]);
}

// per-batch bf16 transpose with input ld: VT[b][d][n] = V[b][n][d]
__global__ void trans_bf16(const unsigned short* __restrict__ V, unsigned short* __restrict__ VT,
                           int rows, int cols, int ld_in, long long sIn, long long sOut) {
  const size_t bi = (size_t)blockIdx.z * sIn;
  const size_t bo = (size_t)blockIdx.z * sOut;
  __shared__ unsigned short tile[32][33];
  const int c0 = blockIdx.x * 32, r0 = blockIdx.y * 32;
  const int tx = threadIdx.x, ty = threadIdx.y;
  #pragma unroll
  for (int r = ty; r < 32; r += 8)
    tile[r][tx] = V[bi + (size_t)(r0 + r) * ld_in + (c0 + tx)];
  __syncthreads();
  #pragma unroll
  for (int r = ty; r < 32; r += 8)
    VT[bo + (size_t)(c0 + r) * rows + (r0 + tx)] = tile[tx][r];
}

// causal row softmax, single-pass: row (N=2048 fp32) in registers (8/thread)
__global__ __launch_bounds__(256) void softmax_causal(
    const float* __restrict__ S, unsigned short* __restrict__ att, int N, float scale) {
  const int row = blockIdx.x;
  const int b = row / N;
  const int r = row - b * N;
  const float* s = S + (size_t)b * N * N + (size_t)r * N;
  unsigned short* a = att + (size_t)b * N * N + (size_t)r * N;
  const int L = r + 1;
  const int Lpad = (L + 127) & ~127;   // PV (128-tile) reads k < roundup(row+1,128)
  const int tid = threadIdx.x;
  const int j0 = tid * 8;
  const bool active = j0 < Lpad;

  float v[8];
  if (active) {
    const float4 p0 = *reinterpret_cast<const float4*>(s + j0);
    const float4 p1 = *reinterpret_cast<const float4*>(s + j0 + 4);
    v[0] = p0.x; v[1] = p0.y; v[2] = p0.z; v[3] = p0.w;
    v[4] = p1.x; v[5] = p1.y; v[6] = p1.z; v[7] = p1.w;
  }

  __shared__ float redm[4], reds[4];

  float mx = -3.0e38f;
  if (active) {
    #pragma unroll
    for (int k = 0; k < 8; ++k) mx = fmaxf(mx, (j0 + k < L) ? v[k] : -3.0e38f);
  }
  #pragma unroll
  for (int o = 32; o > 0; o >>= 1) mx = fmaxf(mx, __shfl_xor(mx, o, 64));
  if ((tid & 63) == 0) redm[tid >> 6] = mx;
  __syncthreads();
  mx = fmaxf(fmaxf(redm[0], redm[1]), fmaxf(redm[2], redm[3]));

  float e[8];
  float sum = 0.f;
  if (active) {
    #pragma unroll
    for (int k = 0; k < 8; ++k) {
      e[k] = (j0 + k < L) ? __expf((v[k] - mx) * scale) : 0.f;
      sum += e[k];
    }
  }
  #pragma unroll
  for (int o = 32; o > 0; o >>= 1) sum += __shfl_xor(sum, o, 64);
  if ((tid & 63) == 0) reds[tid >> 6] = sum;
  __syncthreads();
  sum = reds[0] + reds[1] + reds[2] + reds[3];
  const float inv = 1.f / sum;

  if (active) {
    uint4 w;
    unsigned int t0 = f2bf(e[0] * inv), t1 = f2bf(e[1] * inv);
    unsigned int t2 = f2bf(e[2] * inv), t3 = f2bf(e[3] * inv);
    unsigned int t4 = f2bf(e[4] * inv), t5 = f2bf(e[5] * inv);
    unsigned int t6 = f2bf(e[6] * inv), t7 = f2bf(e[7] * inv);
    w.x = t0 | (t1 << 16); w.y = t2 | (t3 << 16);
    w.z = t4 | (t5 << 16); w.w = t6 | (t7 << 16);
    *reinterpret_cast<uint4*>(a + j0) = w;
  }
}

// h = LN(attout + v) * gamma + beta  (D=1024, 256 thr x 4 contiguous)
__global__ __launch_bounds__(256) void add_layernorm(
    const unsigned short* __restrict__ ao, const unsigned short* __restrict__ qkv,
    int ldv, int voff,
    const float* __restrict__ gamma, const float* __restrict__ beta,
    unsigned short* __restrict__ h) {
  const size_t base  = (size_t)blockIdx.x * 1024;
  const size_t vbase = (size_t)blockIdx.x * ldv + voff;
  const int tid = threadIdx.x;
  const int j = tid * 4;

  const ushort4 a4 = *reinterpret_cast<const ushort4*>(ao + base + j);
  const ushort4 v4 = *reinterpret_cast<const ushort4*>(qkv + vbase + j);
  float xv[4];
  xv[0] = bf2f(a4.x) + bf2f(v4.x);
  xv[1] = bf2f(a4.y) + bf2f(v4.y);
  xv[2] = bf2f(a4.z) + bf2f(v4.z);
  xv[3] = bf2f(a4.w) + bf2f(v4.w);
  float sum = xv[0] + xv[1] + xv[2] + xv[3];
  float sq  = xv[0]*xv[0] + xv[1]*xv[1] + xv[2]*xv[2] + xv[3]*xv[3];

  #pragma unroll
  for (int o = 32; o > 0; o >>= 1) { sum += __shfl_xor(sum, o, 64); sq += __shfl_xor(sq, o, 64); }
  __shared__ float rs_[4], rq_[4];
  if ((tid & 63) == 0) { rs_[tid >> 6] = sum; rq_[tid >> 6] = sq; }
  __syncthreads();
  sum = rs_[0] + rs_[1] + rs_[2] + rs_[3];
  sq  = rq_[0] + rq_[1] + rq_[2] + rq_[3];
  const float mu   = sum * (1.f / 1024.f);
  const float var  = sq * (1.f / 1024.f) - mu * mu;
  const float rstd = rsqrtf(var + 1e-5f);

  const float4 g4 = *reinterpret_cast<const float4*>(gamma + j);
  const float4 b4 = *reinterpret_cast<const float4*>(beta + j);
  ushort4 o4;
  o4.x = f2bf((xv[0] - mu) * rstd * g4.x + b4.x);
  o4.y = f2bf((xv[1] - mu) * rstd * g4.y + b4.y);
  o4.z = f2bf((xv[2] - mu) * rstd * g4.z + b4.z);
  o4.w = f2bf((xv[3] - mu) * rstd * g4.w + b4.w);
  *reinterpret_cast<ushort4*>(h + base + j) = o4;
}

// ---------- launch ----------
extern "C" void kernel_launch(void* const* d_in, const int* in_sizes, int n_in,
                              void* d_out, int out_size, void* d_ws, size_t ws_size,
                              hipStream_t stream) {
  const float* x     = (const float*)d_in[0];
  const float* Wq    = (const float*)d_in[1];
  const float* Wk    = (const float*)d_in[2];
  const float* Wv    = (const float*)d_in[3];
  const float* Wfc   = (const float*)d_in[4];
  const float* bfc   = (const float*)d_in[5];
  const float* gamma = (const float*)d_in[6];
  const float* beta  = (const float*)d_in[7];
  float* out = (float*)d_out;

  const int Bn = 4, Nn = 2048, Dn = 1024;
  const int M = Bn * Nn;                       // 8192
  const int D3 = 3 * Dn;                       // 3072

  char* ws = (char*)d_ws;
  size_t off = 0;
  auto alloc = [&](size_t bytes) { void* p = ws + off; off += (bytes + 255) & ~255ULL; return p; };
  unsigned short* xb    = (unsigned short*)alloc((size_t)M * Dn * 2);        // 16 MB
  unsigned short* WqkvT = (unsigned short*)alloc((size_t)D3 * Dn * 2);       // 6 MB
  unsigned short* WfcT  = (unsigned short*)alloc((size_t)Dn * Dn * 2);       // 2 MB
  unsigned short* QKV   = (unsigned short*)alloc((size_t)M * D3 * 2);        // 48 MB
  unsigned short* VTb   = (unsigned short*)alloc((size_t)M * Dn * 2);        // 16 MB
  float*          S     = (float*)alloc((size_t)Bn * Nn * Nn * 4);           // 64 MB
  unsigned short* att   = (unsigned short*)alloc((size_t)Bn * Nn * Nn * 2);  // 32 MB
  // S is dead after softmax -> reuse for ao and h
  unsigned short* ao = (unsigned short*)S;
  unsigned short* h  = (unsigned short*)S + (size_t)M * Dn;

  unsigned short* Qp = QKV;               // ld D3
  unsigned short* Kp = QKV + Dn;          // ld D3
  unsigned short* Vp = QKV + 2 * Dn;      // ld D3

  const dim3 blk(256), blk8(512);

  // 1. casts
  cast_f32_bf16<<<dim3(((long long)M * Dn) / 1024), blk, 0, stream>>>(x, xb, (long long)M * Dn);
  const dim3 tb(32, 8, 1);
  transcast_w4<<<dim3(Dn / 32, Dn / 32, 4), tb, 0, stream>>>(
      Wq, Wk, Wv, Wfc,
      WqkvT, WqkvT + (size_t)Dn * Dn, WqkvT + (size_t)2 * Dn * Dn, WfcT, Dn, Dn);

  // 2. fused QKV projection: [8192,1024] x [3072,1024]^T -> bf16 (256² phased)
  gemm8_bt<1, false><<<dim3(D3 / BN8, M / BM8, 1), blk8, 0, stream>>>(
      xb, WqkvT, QKV, nullptr, Dn, Dn, Dn, D3, 0, 0, 0);

  // 3. V^T for PV
  trans_bf16<<<dim3(Dn / 32, Nn / 32, Bn), tb, 0, stream>>>(
      Vp, VTb, Nn, Dn, D3, (long long)Nn * D3, (long long)Dn * Nn);

  // 4. scores = Q K^T (lower-triangle 256² tiles), fp32 (256² phased)
  gemm8_bt<0, true><<<dim3(Nn / BN8, Nn / BM8, Bn), blk8, 0, stream>>>(
      Qp, Kp, S, nullptr, Dn, D3, D3, Nn,
      (long long)Nn * D3, (long long)Nn * D3, (long long)Nn * Nn);

  // 5. causal softmax -> bf16 att (zero-padded to 128 boundary)
  softmax_causal<<<dim3(Bn * Nn), blk, 0, stream>>>(S, att, Nn, 0.03125f);

  // 6. attout = att @ V  (128² kernel, K limited to diagonal block)
  gemm_bt<1, false, true><<<dim3(Dn / BN, Nn / BM, Bn), blk, 0, stream>>>(
      att, VTb, ao, nullptr, Nn, Nn, Nn, Dn,
      (long long)Nn * Nn, (long long)Dn * Nn, (long long)Nn * Dn);

  // 7. h = LN(attout + v)
  add_layernorm<<<dim3(Bn * Nn), blk, 0, stream>>>(ao, QKV, D3, 2 * Dn, gamma, beta, h);

  // 8. out = h @ Wfc + bfc, fp32 (256² phased)
  gemm8_bt<2, false><<<dim3(Dn / BN8, M / BM8, 1), blk8, 0, stream>>>(
      h, WfcT, out, bfc, Dn, Dn, Dn, Dn, 0, 0, 0);
}